// Round 9
// baseline (50.129 us; speedup 1.0000x reference)
//
#include <hip/hip_runtime.h>

// Per-channel piecewise-linear calibration, real part only (out_size == N).
// x_real: [B=4, C=128, H=256, W=256] f32; xp,yp: [C=128, K=101] f32, xp sorted.
//
// Branchless depth-2 eval (exact searchsorted-right):
//   c8  = #(register pivots xp[8m] <= x)          -- pure VALU
//   cnt = 8*c8 + #(xp_s[8*c8 .. 8*c8+7] <= x)     -- one aligned 8f window read
//   j   = clamp(cnt-1, 0, 99); y = fma(x, a_j, b_j)
// Round 9: two independent f32x4 chains per iter (8 elements in flight/thread),
// CPB 8192 to halve prologue overhead.

#define K_BP    101
#define K_PAD   128
#define NCH     128
#define HW      65536
#define BLK     256
#define CPB     8192                   // elements per block (8 blocks/plane)
#define ITERS   4                      // per iter: 2 f32x4 per thread
#define NPIV    12                     // pivots xp[8], xp[16], ..., xp[96]

typedef float f32x4 __attribute__((ext_vector_type(4)));

__device__ __forceinline__ f32x4 pwl4(f32x4 v, const float* __restrict__ piv,
                                      const float* __restrict__ xp_s,
                                      const float2* __restrict__ ab_s) {
    f32x4 o;
    #pragma unroll
    for (int e = 0; e < 4; ++e) {
        float x = v[e];
        int c8 = 0;
        #pragma unroll
        for (int m = 0; m < NPIV; ++m) c8 += (x >= piv[m]) ? 1 : 0;
        const int wbase = 8 * c8;              // 0..96, 32B-aligned window
        const f32x4 w0 = *reinterpret_cast<const f32x4*>(xp_s + wbase);
        const f32x4 w1 = *reinterpret_cast<const f32x4*>(xp_s + wbase + 4);
        int cnt = wbase;
        cnt += (x >= w0.x) ? 1 : 0;  cnt += (x >= w0.y) ? 1 : 0;
        cnt += (x >= w0.z) ? 1 : 0;  cnt += (x >= w0.w) ? 1 : 0;
        cnt += (x >= w1.x) ? 1 : 0;  cnt += (x >= w1.y) ? 1 : 0;
        cnt += (x >= w1.z) ? 1 : 0;  cnt += (x >= w1.w) ? 1 : 0;
        int j = cnt - 1;
        j = j < 0 ? 0 : j;
        j = j > (K_BP - 2) ? (K_BP - 2) : j;   // clamp -> extrapolation
        float2 ab = ab_s[j];
        o[e] = fmaf(x, ab.x, ab.y);
    }
    return o;
}

__global__ __launch_bounds__(BLK) void pwl_real_kernel(
    const float* __restrict__ xr,
    const float* __restrict__ xp, const float* __restrict__ yp,
    float* __restrict__ out)
{
    __shared__ __align__(16) float  xp_s[K_PAD];     // +inf padded breakpoints
    __shared__ __align__(16) float2 ab_s[K_BP - 1];  // per-segment (a, b)

    const int t     = threadIdx.x;
    const int bid   = blockIdx.x;
    const int plane = bid >> 3;                // 8 blocks per (b,c) plane
    const int chunk = bid & 7;
    const int c     = plane & (NCH - 1);
    const unsigned int base = (unsigned int)plane * HW + (unsigned int)chunk * CPB;

    if (t < K_PAD) {
        xp_s[t] = (t < K_BP) ? xp[c * K_BP + t] : __builtin_inff();
    }
    __syncthreads();

    // Per-segment a = (y1-y0)/(x1-x0) (ref arithmetic), b = y0 - x0*a.
    if (t < K_BP - 1) {
        float x0 = xp_s[t], x1 = xp_s[t + 1];
        float y0 = yp[c * K_BP + t], y1 = yp[c * K_BP + t + 1];
        float a  = (y1 - y0) / (x1 - x0);
        ab_s[t]  = make_float2(a, fmaf(-x0, a, y0));
    }

    // Block-uniform pivots -> registers (broadcast LDS reads, once).
    float piv[NPIV];
    #pragma unroll
    for (int m = 0; m < NPIV; ++m) piv[m] = xp_s[8 * (m + 1)];
    __syncthreads();

    #pragma unroll
    for (int it = 0; it < ITERS; ++it) {
        // Two independent chains per iteration: stripes 2*it and 2*it+1.
        const unsigned int gA = base + ((unsigned int)(2 * it)     * BLK + t) * 4;
        const unsigned int gB = base + ((unsigned int)(2 * it + 1) * BLK + t) * 4;
        f32x4 vA = *reinterpret_cast<const f32x4*>(xr + gA);
        f32x4 vB = *reinterpret_cast<const f32x4*>(xr + gB);
        f32x4 oA = pwl4(vA, piv, xp_s, ab_s);
        f32x4 oB = pwl4(vB, piv, xp_s, ab_s);
        *reinterpret_cast<f32x4*>(out + gA) = oA;
        *reinterpret_cast<f32x4*>(out + gB) = oB;
    }
}

extern "C" void kernel_launch(void* const* d_in, const int* in_sizes, int n_in,
                              void* d_out, int out_size, void* d_ws, size_t ws_size,
                              hipStream_t stream) {
    const float* xr = (const float*)d_in[0];
    const float* xp = (const float*)d_in[2];
    const float* yp = (const float*)d_in[3];
    float* out = (float*)d_out;

    const long long N = (long long)in_sizes[0];   // 33,554,432
    const int blocks = (int)(N / CPB);            // 4096
    pwl_real_kernel<<<dim3(blocks), dim3(BLK), 0, stream>>>(xr, xp, yp, out);
}

// Round 10
// 47.872 us; speedup vs baseline: 1.0472x; 1.0472x over previous
//
#include <hip/hip_runtime.h>

// Per-channel piecewise-linear calibration, real part only (out_size == N).
// x_real: [B=4, C=128, H=256, W=256] f32; xp,yp: [C=128, K=101] f32, xp sorted.
//
// Round-10: restore the empirically-best round-2 kernel (47.5 us). Three
// structurally different variants (r2 LDS-search, r8 pivot-count, r9 ILP)
// all land 47.5-50 us with wildly different core-side counters -> the limit
// is the memory system (268 MB mandatory traffic at ~90% of copy ceiling).

#define K_BP    101
#define K_PAD   128
#define NCH     128
#define HW      65536      // H*W, contiguous elements per (b,c) plane
#define BLK     256
#define CPB     4096       // elements per block (16 blocks/plane)
#define ITERS   (CPB / (BLK * 4))   // 4 iters, one float4 per thread per iter

typedef float f32x4 __attribute__((ext_vector_type(4)));

__device__ __forceinline__ float pwl_eval(float x,
                                          const float* __restrict__ xp_s,
                                          const float2* __restrict__ seg_s) {
    // lo = count(xp <= x) == searchsorted(xp, x, side='right'); pad is +inf.
    int lo = 0;
    #pragma unroll
    for (int step = 64; step >= 1; step >>= 1) {
        lo += (xp_s[lo + step - 1] <= x) ? step : 0;   // max idx 126 < 128
    }
    int j = lo - 1;
    j = j < 0 ? 0 : j;
    j = j > (K_BP - 2) ? (K_BP - 2) : j;   // clamp -> linear extrapolation at ends
    float2 s = seg_s[j];                    // (y0, slope)
    return fmaf(x - xp_s[j], s.y, s.x);
}

__global__ __launch_bounds__(BLK) void pwl_real_kernel(
    const float* __restrict__ xr,
    const float* __restrict__ xp, const float* __restrict__ yp,
    float* __restrict__ out)
{
    __shared__ float  xp_s[K_PAD];
    __shared__ float2 seg_s[K_BP - 1];

    const int t     = threadIdx.x;
    const int bid   = blockIdx.x;
    const int plane = bid >> 4;            // 16 blocks per plane
    const int chunk = bid & 15;
    const int c     = plane & (NCH - 1);
    const long long base = (long long)plane * HW + (long long)chunk * CPB;

    // Stage breakpoints (+inf pad so count(xp<=x) ignores the pad).
    if (t < K_PAD) {
        xp_s[t] = (t < K_BP) ? xp[c * K_BP + t] : __builtin_inff();
    }
    __syncthreads();
    // Per-segment (y0, slope): same arithmetic as the reference.
    if (t < K_BP - 1) {
        float y0 = yp[c * K_BP + t];
        float y1 = yp[c * K_BP + t + 1];
        seg_s[t] = make_float2(y0, (y1 - y0) / (xp_s[t + 1] - xp_s[t]));
    }
    __syncthreads();

    #pragma unroll
    for (int it = 0; it < ITERS; ++it) {
        const long long g = base + (long long)it * (BLK * 4) + (long long)t * 4;
        f32x4 v = *reinterpret_cast<const f32x4*>(xr + g);
        f32x4 o;
        o.x = pwl_eval(v.x, xp_s, seg_s);
        o.y = pwl_eval(v.y, xp_s, seg_s);
        o.z = pwl_eval(v.z, xp_s, seg_s);
        o.w = pwl_eval(v.w, xp_s, seg_s);
        *reinterpret_cast<f32x4*>(out + g) = o;
    }
}

extern "C" void kernel_launch(void* const* d_in, const int* in_sizes, int n_in,
                              void* d_out, int out_size, void* d_ws, size_t ws_size,
                              hipStream_t stream) {
    const float* xr = (const float*)d_in[0];
    const float* xp = (const float*)d_in[2];
    const float* yp = (const float*)d_in[3];
    float* out = (float*)d_out;

    const long long N = (long long)in_sizes[0];   // 33,554,432
    const int blocks = (int)(N / CPB);            // 8192
    pwl_real_kernel<<<dim3(blocks), dim3(BLK), 0, stream>>>(xr, xp, yp, out);
}